// Round 13
// baseline (108.879 us; speedup 1.0000x reference)
//
#include <hip/hip_runtime.h>
#include <hip/hip_bf16.h>
#include <math.h>

#define B_ 4096
#define D_ 784
#define C_ 10
#define E_ 1024
#define K_ 8
#define KP 832      // D padded to 13*64 for MFMA/BK=64
#define CHR 104     // 8-short chunks per padded row (KP/8); 98 hold data
#define NW 1088     // kh rows / cosb width: 1024 keys + 10 Wv + 10 Wt + 44 pad (17*64)
#define LDR 72      // gemm LDS row stride (shorts): 2-way bank aliasing (free)
#define LDW 840     // expert LDS row stride (shorts)
#define CAP 48      // candidate capacity in topk_select
#define ECAP 128    // per-expert bucket capacity
#define MARG 0.04f  // ~8 sigma of bf16-dot error (sigma_dot = 1)

typedef float f32x4 __attribute__((ext_vector_type(4)));
typedef short s16x8 __attribute__((ext_vector_type(8)));

__device__ __forceinline__ float wave_reduce_sum(float v) {
  #pragma unroll
  for (int off = 32; off > 0; off >>= 1) v += __shfl_xor(v, off, 64);
  return v;
}

__device__ __forceinline__ float bitonic64_f(float v, int lane) {
  #pragma unroll
  for (int k = 2; k <= 64; k <<= 1)
    #pragma unroll
    for (int j = k >> 1; j > 0; j >>= 1) {
      float o = __shfl_xor(v, j, 64);
      bool keepmin = ((lane & j) == 0) == ((lane & k) == 0);
      v = keepmin ? fminf(v, o) : fmaxf(v, o);
    }
  return v;
}

__device__ __forceinline__ unsigned long long bitonic64_u(unsigned long long v, int lane) {
  #pragma unroll
  for (int k = 2; k <= 64; k <<= 1)
    #pragma unroll
    for (int j = k >> 1; j > 0; j >>= 1) {
      unsigned long long o = __shfl_xor(v, j, 64);
      bool keepmin = ((lane & j) == 0) == ((lane & k) == 0);
      v = keepmin ? (v < o ? v : o) : (v < o ? o : v);
    }
  return v;
}

__device__ __forceinline__ unsigned long long packkey(float v, int idx) {
  unsigned ub = __float_as_uint(v);
  ub = (ub & 0x80000000u) ? ~ub : (ub | 0x80000000u);
  return ((unsigned long long)ub << 32) | (unsigned)(~idx);
}
__device__ __forceinline__ float unpackval(unsigned long long k) {
  unsigned ub = (unsigned)(k >> 32);
  unsigned fb = (ub & 0x80000000u) ? (ub ^ 0x80000000u) : ~ub;
  return __uint_as_float(fb);
}

// ---- fused prep: bf16-convert x -> xh, {keys,Wv,Wt} -> kh rows; zero count + out_ens ----
__global__ __launch_bounds__(256) void prep_all(const float* __restrict__ x,
                                                const float* __restrict__ keys,
                                                const float* __restrict__ Wv,
                                                const float* __restrict__ Wt,
                                                unsigned short* __restrict__ xh,
                                                unsigned short* __restrict__ kh,
                                                float* __restrict__ out_ens,
                                                int* __restrict__ count) {
  int gt = blockIdx.x * 256 + threadIdx.x;
  if (gt < E_) count[gt] = 0;
  int t = gt;
  const float* src = nullptr;
  unsigned short* dst;
  if (t < B_ * CHR) {
    int row = t / CHR, ch = t % CHR;
    dst = xh + (size_t)row * KP + ch * 8;
    src = (ch < 98) ? x + (size_t)row * D_ + ch * 8 : nullptr;
  } else {
    t -= B_ * CHR;
    if (t < NW * CHR) {
      int row = t / CHR, ch = t % CHR;
      dst = kh + (size_t)row * KP + ch * 8;
      if (ch < 98) {
        if (row < E_) src = keys + (size_t)row * D_ + ch * 8;
        else if (row < E_ + 10) src = Wv + (size_t)(row - E_) * D_ + ch * 8;
        else if (row < E_ + 20) src = Wt + (size_t)(row - E_ - 10) * D_ + ch * 8;
      }
    } else {
      t -= NW * CHR;
      if (t < (B_ * C_) / 4) {
        float4 z = make_float4(0.f, 0.f, 0.f, 0.f);
        ((float4*)out_ens)[t] = z;
      }
      return;
    }
  }
  unsigned short u[8];
  if (src) {
    #pragma unroll
    for (int i = 0; i < 8; ++i) {
      __hip_bfloat16 h = __float2bfloat16(src[i]);
      u[i] = *(unsigned short*)&h;
    }
  } else {
    #pragma unroll
    for (int i = 0; i < 8; ++i) u[i] = 0;
  }
  *(uint4*)dst = *(uint4*)u;
}

// ------ routing+heads GEMM: [4096,832]x[1088,832]^T bf16, 64x64 tile, BK=64,
//        XCD-swizzled blockIdx (1088 = 8 x 136, bijective) ------
__global__ __launch_bounds__(256) void gemm_bf16(const unsigned short* __restrict__ xh,
                                                 const unsigned short* __restrict__ kh,
                                                 float* __restrict__ cosb) {
  __shared__ unsigned short As[64 * LDR];
  __shared__ unsigned short Bs[64 * LDR];
  const int tid  = threadIdx.x;
  const int bid  = blockIdx.y * 17 + blockIdx.x;      // 0..1087
  const int swz  = (bid & 7) * 136 + (bid >> 3);      // XCD-contiguous chunks
  const int row0 = (swz / 17) * 64, col0 = (swz % 17) * 64;
  const int srow = tid >> 2, sq = tid & 3;            // staging: row, quarter
  const int lane = tid & 63, w = tid >> 6;
  const int wr = (w >> 1) * 32, wc = (w & 1) * 32;
  const int fr = lane & 15, fg = lane >> 4;

  const unsigned short* gx = xh + (size_t)(row0 + srow) * KP;
  const unsigned short* gk = kh + (size_t)(col0 + srow) * KP;
  unsigned short* sa = As + srow * LDR + sq * 8;      // chunks at sq*8 and 32+sq*8
  unsigned short* sb = Bs + srow * LDR + sq * 8;
  const unsigned short* pa0 = As + (wr + fr) * LDR + fg * 8;
  const unsigned short* pb0 = Bs + (wc + fr) * LDR + fg * 8;

  uint4 va0 = *(const uint4*)(gx + sq * 8);
  uint4 va1 = *(const uint4*)(gx + 32 + sq * 8);
  uint4 vb0 = *(const uint4*)(gk + sq * 8);
  uint4 vb1 = *(const uint4*)(gk + 32 + sq * 8);

  f32x4 acc[2][2] = {};
  for (int t = 0; t < 13; ++t) {
    __syncthreads();
    *(uint4*)sa = va0; *(uint4*)(sa + 32) = va1;
    *(uint4*)sb = vb0; *(uint4*)(sb + 32) = vb1;
    __syncthreads();
    if (t < 12) {
      int k1 = (t + 1) * 64;
      va0 = *(const uint4*)(gx + k1 + sq * 8);
      va1 = *(const uint4*)(gx + k1 + 32 + sq * 8);
      vb0 = *(const uint4*)(gk + k1 + sq * 8);
      vb1 = *(const uint4*)(gk + k1 + 32 + sq * 8);
    }
    #pragma unroll
    for (int kk = 0; kk < 64; kk += 32) {
      s16x8 a0 = *(const s16x8*)(pa0 + kk);
      s16x8 a1 = *(const s16x8*)(pa0 + 16 * LDR + kk);
      s16x8 b0 = *(const s16x8*)(pb0 + kk);
      s16x8 b1 = *(const s16x8*)(pb0 + 16 * LDR + kk);
      acc[0][0] = __builtin_amdgcn_mfma_f32_16x16x32_bf16(a0, b0, acc[0][0], 0, 0, 0);
      acc[0][1] = __builtin_amdgcn_mfma_f32_16x16x32_bf16(a0, b1, acc[0][1], 0, 0, 0);
      acc[1][0] = __builtin_amdgcn_mfma_f32_16x16x32_bf16(a1, b0, acc[1][0], 0, 0, 0);
      acc[1][1] = __builtin_amdgcn_mfma_f32_16x16x32_bf16(a1, b1, acc[1][1], 0, 0, 0);
    }
  }
  #pragma unroll
  for (int m = 0; m < 2; ++m)
    #pragma unroll
    for (int n = 0; n < 2; ++n)
      #pragma unroll
      for (int j = 0; j < 4; ++j) {
        int r = row0 + wr + m * 16 + fg * 4 + j;
        int c = col0 + wc + n * 16 + fr;
        cosb[(size_t)r * NW + c] = acc[m][n][j];
      }
}

// ---- topk: one WAVE per row. Approx dots are the weights (scale-invariant ensemble);
//      exact fp32 refine only for boundary-ambiguous candidates. Heads fused. ----
__global__ __launch_bounds__(256) void topk_select(const float* __restrict__ cosb,
                                                   const float* __restrict__ x,
                                                   const float* __restrict__ keys,
                                                   const float* __restrict__ bv,
                                                   const float* __restrict__ bt,
                                                   float* __restrict__ sims,
                                                   int* __restrict__ count,
                                                   int* __restrict__ list,
                                                   float* __restrict__ out_tanh,
                                                   float* __restrict__ out_van) {
  __shared__ unsigned long long sKey[4][CAP];
  const int tid = threadIdx.x, w = tid >> 6, lane = tid & 63;
  const int row = (blockIdx.x << 2) + w;
  const float* cr = cosb + (size_t)row * NW;

  // ---- heads epilogue from cosb cols 1024..1043 ----
  {
    float hv = (lane < 20) ? cr[E_ + lane] : 0.f;
    float vv = 0.f, tv = 0.f;
    if (lane < 10) vv = hv + bv[lane];
    else if (lane < 20) tv = hv + bt[lane - 10];
    float mv = (lane < 10) ? vv : -__builtin_inff();
    #pragma unroll
    for (int off = 1; off < 16; off <<= 1) mv = fmaxf(mv, __shfl_xor(mv, off, 64));
    float ev = (lane < 10) ? expf(vv - mv) : 0.f;
    float se = ev;
    #pragma unroll
    for (int off = 1; off < 16; off <<= 1) se += __shfl_xor(se, off, 64);
    if (lane < 10) out_van[(size_t)row * C_ + lane] = vv - (mv + logf(se));
    else if (lane < 20) out_tanh[(size_t)row * C_ + (lane - 10)] = tanhf(tv * 0.1f) * 10.0f;
  }

  // ---- load the 1024 routing dots (cols 0..1023 only) ----
  float vals[16];
  #pragma unroll
  for (int j = 0; j < 16; ++j) vals[j] = cr[j * 64 + lane];
  float lm = vals[0];
  #pragma unroll
  for (int j = 1; j < 16; ++j) lm = fmaxf(lm, vals[j]);

  // threshold: 8th largest lane-max <= 8th largest value
  float srt = bitonic64_f(lm, lane);
  const float thr = __shfl(srt, 56) - MARG;

  // compact candidates (deterministic ballot-prefix order)
  int cnt = 0;
  #pragma unroll
  for (int j = 0; j < 16; ++j) {
    bool p = vals[j] >= thr;
    unsigned long long mk = __ballot(p);
    if (p) {
      int pos = cnt + __popcll(mk & ((1ull << lane) - 1ull));
      if (pos < CAP) sKey[w][pos] = packkey(vals[j], j * 64 + lane);
    }
    cnt += __popcll(mk);
  }
  const int m = cnt < CAP ? cnt : CAP;

  unsigned long long key = (lane < m) ? sKey[w][lane] : 0ull;
  key = bitonic64_u(key, lane);       // ascending; lanes 56..63 = approx top-8

  const float a8 = unpackval(__shfl(key, 56));
  const float a9 = unpackval(__shfl(key, 55));   // NaN if m == 8 (key 0)

  if (a8 - a9 <= MARG) {              // wave-uniform; false when a9 is NaN
    // boundary ambiguous: exact fp32 refine of window candidates
    const float4* xp4 = (const float4*)(x + (size_t)row * D_);
    float4 xr[4];
    #pragma unroll
    for (int i = 0; i < 3; ++i) xr[i] = xp4[i * 64 + lane];
    xr[3] = make_float4(0.f, 0.f, 0.f, 0.f);
    if (lane < 4) xr[3] = xp4[192 + lane];

    float myv = unpackval(key);
    unsigned long long rm = __ballot(key != 0ull && fabsf(myv - a8) <= MARG);
    while (rm) {
      int L = __builtin_ctzll(rm);
      rm &= rm - 1;
      unsigned long long kL = __shfl(key, L);
      int ei = (int)(~(unsigned)kL) & (E_ - 1);
      const float4* kp4 = (const float4*)(keys + (size_t)ei * D_);
      float s = 0.f;
      #pragma unroll
      for (int i = 0; i < 3; ++i) {
        float4 kv = kp4[i * 64 + lane];
        s += xr[i].x * kv.x + xr[i].y * kv.y + xr[i].z * kv.z + xr[i].w * kv.w;
      }
      if (lane < 4) {
        float4 kv = kp4[192 + lane];
        s += xr[3].x * kv.x + xr[3].y * kv.y + xr[3].z * kv.z + xr[3].w * kv.w;
      }
      s = wave_reduce_sum(s);
      if (lane == L) key = packkey(s, ei);
    }
    key = bitonic64_u(key, lane);     // re-rank with exact boundary values
  }

  // emit top-8: normalized weights by value-rank, bucket scatter by ascending id
  if (lane >= 56) {
    float simv = unpackval(key);
    int ei = (int)(~(unsigned)key) & (E_ - 1);
    float ssum = simv;
    ssum += __shfl_xor(ssum, 1, 64);
    ssum += __shfl_xor(ssum, 2, 64);
    ssum += __shfl_xor(ssum, 4, 64);
    sims[row * K_ + (63 - lane)] = simv / ssum;   // rank 0 = best
    int si = ei;
    const int l3 = lane & 7;
    #pragma unroll
    for (int k = 2; k <= 8; k <<= 1) {
      #pragma unroll
      for (int j = k >> 1; j > 0; j >>= 1) {
        int o = __shfl_xor(si, j, 64);
        bool lower = (l3 & j) == 0;
        bool asc = (l3 & k) == 0;
        int mn = si < o ? si : o;
        int mx = si < o ? o : si;
        si = (lower == asc) ? mn : mx;
      }
    }
    int pos = atomicAdd(&count[si], 1);
    if (pos < ECAP) list[si * ECAP + pos] = row * K_ + (lane - 56);
  }
}

// ---- per-expert bf16 MFMA: X_e @ W_e^T -> tanh -> weighted atomic scatter into out ----
__global__ __launch_bounds__(256) void expert_mfma(const float* __restrict__ Wm,
                                                   const float* __restrict__ bm,
                                                   const unsigned short* __restrict__ xh,
                                                   const int* __restrict__ list,
                                                   const int* __restrict__ count,
                                                   const float* __restrict__ sims,
                                                   float* __restrict__ out_ens) {
  __shared__ unsigned short Wl[16 * LDW];
  const int e   = blockIdx.x;
  const int tid = threadIdx.x;
  int n = count[e];
  n = n < ECAP ? n : ECAP;
  const int base = e * ECAP;

  for (int ch = tid; ch < 16 * CHR; ch += 256) {
    int r  = ch / CHR;
    int kc = (ch % CHR) * 8;
    unsigned short u[8];
    if (r < 10 && kc < 784) {
      const float4* s4 = (const float4*)(Wm + (size_t)e * (C_ * D_) + r * D_ + kc);
      float4 f0 = s4[0], f1 = s4[1];
      __hip_bfloat16 h;
      h = __float2bfloat16(f0.x); u[0] = *(unsigned short*)&h;
      h = __float2bfloat16(f0.y); u[1] = *(unsigned short*)&h;
      h = __float2bfloat16(f0.z); u[2] = *(unsigned short*)&h;
      h = __float2bfloat16(f0.w); u[3] = *(unsigned short*)&h;
      h = __float2bfloat16(f1.x); u[4] = *(unsigned short*)&h;
      h = __float2bfloat16(f1.y); u[5] = *(unsigned short*)&h;
      h = __float2bfloat16(f1.z); u[6] = *(unsigned short*)&h;
      h = __float2bfloat16(f1.w); u[7] = *(unsigned short*)&h;
    } else {
      #pragma unroll
      for (int i = 0; i < 8; ++i) u[i] = 0;
    }
    *(uint4*)(Wl + r * LDW + kc) = *(uint4*)u;
  }
  __syncthreads();
  if (n == 0) return;

  const int lane = tid & 63, w = tid >> 6;
  const int fr = lane & 15, fg = lane >> 4;
  const float bias = (fr < C_) ? bm[e * C_ + fr] : 0.f;
  const unsigned short* bp = Wl + fr * LDW + fg * 8;

  for (int c0 = w * 16; c0 < n; c0 += 64) {
    int sidx = c0 + fr;
    int item = (sidx < n) ? list[base + sidx] : list[base];
    const unsigned short* xrow = xh + (size_t)(item >> 3) * KP + fg * 8;
    f32x4 acc = {};
    #pragma unroll
    for (int k0 = 0; k0 < KP; k0 += 32) {
      s16x8 a = *(const s16x8*)(xrow + k0);
      s16x8 b = *(const s16x8*)(bp + k0);
      acc = __builtin_amdgcn_mfma_f32_16x16x32_bf16(a, b, acc, 0, 0, 0);
    }
    if (fr < C_) {
      #pragma unroll
      for (int j = 0; j < 4; ++j) {
        int s2 = c0 + fg * 4 + j;
        if (s2 < n) {
          int it2 = list[base + s2];
          float sc = sims[it2];
          float val = tanhf((acc[j] + bias) * 0.1f) * 10.0f;
          atomicAdd(&out_ens[(size_t)(it2 >> 3) * C_ + fr], val * sc);
        }
      }
    }
  }
}

extern "C" void kernel_launch(void* const* d_in, const int* in_sizes, int n_in,
                              void* d_out, int out_size, void* d_ws, size_t ws_size,
                              hipStream_t stream) {
  const float* x    = (const float*)d_in[0];
  const float* keys = (const float*)d_in[1];
  const float* Wm   = (const float*)d_in[2];
  const float* bm   = (const float*)d_in[3];
  const float* Wv   = (const float*)d_in[4];
  const float* bv   = (const float*)d_in[5];
  const float* Wt   = (const float*)d_in[6];
  const float* bt   = (const float*)d_in[7];
  float* out = (float*)d_out;
  float* out_ens  = out;
  float* out_tanh = out + (size_t)B_ * C_;
  float* out_van  = out + 2 * (size_t)B_ * C_;

  char* p = (char*)d_ws;
  auto carve = [&](size_t bytes) { char* q = p; p += (bytes + 255) & ~(size_t)255; return q; };
  float* cosb  = (float*)carve((size_t)B_ * NW * 4);
  float* sims  = (float*)carve(B_ * K_ * 4);
  unsigned short* xh = (unsigned short*)carve((size_t)B_ * KP * 2);
  unsigned short* kh = (unsigned short*)carve((size_t)NW * KP * 2);
  int*   count  = (int*)carve(E_ * 4);
  int*   list   = (int*)carve((size_t)E_ * ECAP * 4);
  float* eScratch = (float*)carve((size_t)B_ * C_ * 4);  // instrumentation dump

  int prep_threads = B_ * CHR + NW * CHR + (B_ * C_) / 4;
  prep_all<<<(prep_threads + 255) / 256, 256, 0, stream>>>(x, keys, Wv, Wt, xh, kh,
                                                           out_ens, count);
  dim3 g(NW / 64, B_ / 64);   // (17, 64), swizzled inside
  gemm_bf16<<<g, 256, 0, stream>>>(xh, kh, cosb);
  topk_select<<<B_ / 4, 256, 0, stream>>>(cosb, x, keys, bv, bt, sims, count, list,
                                          out_tanh, out_van);
  // --- instrumentation: duplicate expert into scratch (unused) to measure its cost.
  //     dur_us - ~80.7 ≈ expert time. Remove next round. ---
  expert_mfma<<<E_, 256, 0, stream>>>(Wm, bm, xh, list, count, sims, eScratch);
  expert_mfma<<<E_, 256, 0, stream>>>(Wm, bm, xh, list, count, sims, out_ens);
}

// Round 14
// 73.410 us; speedup vs baseline: 1.4832x; 1.4832x over previous
//
#include <hip/hip_runtime.h>
#include <hip/hip_bf16.h>
#include <math.h>

#define B_ 4096
#define D_ 784
#define C_ 10
#define E_ 1024
#define K_ 8
#define KP 832      // D padded to 13*64 for MFMA/BK=64
#define KH 416      // K half (shorts) for expert K-split
#define CHR 104     // 8-short chunks per padded row (KP/8); 98 hold data
#define NW 1088     // kh rows / cosb width: 1024 keys + 10 Wv + 10 Wt + 44 pad (17*64)
#define LDR 72      // gemm LDS row stride (shorts): 2-way bank aliasing (free)
#define LDW 840     // expert LDS row stride (shorts)
#define CAP 48      // candidate capacity in topk_select
#define ECAP 128    // per-expert bucket capacity
#define MARG 0.04f  // ~8 sigma of bf16-dot error (sigma_dot = 1)

typedef float f32x4 __attribute__((ext_vector_type(4)));
typedef short s16x8 __attribute__((ext_vector_type(8)));

__device__ __forceinline__ float wave_reduce_sum(float v) {
  #pragma unroll
  for (int off = 32; off > 0; off >>= 1) v += __shfl_xor(v, off, 64);
  return v;
}

__device__ __forceinline__ float bitonic64_f(float v, int lane) {
  #pragma unroll
  for (int k = 2; k <= 64; k <<= 1)
    #pragma unroll
    for (int j = k >> 1; j > 0; j >>= 1) {
      float o = __shfl_xor(v, j, 64);
      bool keepmin = ((lane & j) == 0) == ((lane & k) == 0);
      v = keepmin ? fminf(v, o) : fmaxf(v, o);
    }
  return v;
}

__device__ __forceinline__ unsigned long long bitonic64_u(unsigned long long v, int lane) {
  #pragma unroll
  for (int k = 2; k <= 64; k <<= 1)
    #pragma unroll
    for (int j = k >> 1; j > 0; j >>= 1) {
      unsigned long long o = __shfl_xor(v, j, 64);
      bool keepmin = ((lane & j) == 0) == ((lane & k) == 0);
      v = keepmin ? (v < o ? v : o) : (v < o ? o : v);
    }
  return v;
}

__device__ __forceinline__ unsigned long long packkey(float v, int idx) {
  unsigned ub = __float_as_uint(v);
  ub = (ub & 0x80000000u) ? ~ub : (ub | 0x80000000u);
  return ((unsigned long long)ub << 32) | (unsigned)(~idx);
}
__device__ __forceinline__ float unpackval(unsigned long long k) {
  unsigned ub = (unsigned)(k >> 32);
  unsigned fb = (ub & 0x80000000u) ? (ub ^ 0x80000000u) : ~ub;
  return __uint_as_float(fb);
}

// ---- fused prep: bf16-convert x -> xh, {keys,Wv,Wt} -> kh rows; zero count + out_ens ----
__global__ __launch_bounds__(256) void prep_all(const float* __restrict__ x,
                                                const float* __restrict__ keys,
                                                const float* __restrict__ Wv,
                                                const float* __restrict__ Wt,
                                                unsigned short* __restrict__ xh,
                                                unsigned short* __restrict__ kh,
                                                float* __restrict__ out_ens,
                                                int* __restrict__ count) {
  int gt = blockIdx.x * 256 + threadIdx.x;
  if (gt < E_) count[gt] = 0;
  int t = gt;
  const float* src = nullptr;
  unsigned short* dst;
  if (t < B_ * CHR) {
    int row = t / CHR, ch = t % CHR;
    dst = xh + (size_t)row * KP + ch * 8;
    src = (ch < 98) ? x + (size_t)row * D_ + ch * 8 : nullptr;
  } else {
    t -= B_ * CHR;
    if (t < NW * CHR) {
      int row = t / CHR, ch = t % CHR;
      dst = kh + (size_t)row * KP + ch * 8;
      if (ch < 98) {
        if (row < E_) src = keys + (size_t)row * D_ + ch * 8;
        else if (row < E_ + 10) src = Wv + (size_t)(row - E_) * D_ + ch * 8;
        else if (row < E_ + 20) src = Wt + (size_t)(row - E_ - 10) * D_ + ch * 8;
      }
    } else {
      t -= NW * CHR;
      if (t < (B_ * C_) / 4) {
        float4 z = make_float4(0.f, 0.f, 0.f, 0.f);
        ((float4*)out_ens)[t] = z;
      }
      return;
    }
  }
  unsigned short u[8];
  if (src) {
    #pragma unroll
    for (int i = 0; i < 8; ++i) {
      __hip_bfloat16 h = __float2bfloat16(src[i]);
      u[i] = *(unsigned short*)&h;
    }
  } else {
    #pragma unroll
    for (int i = 0; i < 8; ++i) u[i] = 0;
  }
  *(uint4*)dst = *(uint4*)u;
}

// ------ routing+heads GEMM: [4096,832]x[1088,832]^T bf16, 64x64 tile, BK=64,
//        XCD-swizzled blockIdx (1088 = 8 x 136, bijective) ------
__global__ __launch_bounds__(256) void gemm_bf16(const unsigned short* __restrict__ xh,
                                                 const unsigned short* __restrict__ kh,
                                                 float* __restrict__ cosb) {
  __shared__ unsigned short As[64 * LDR];
  __shared__ unsigned short Bs[64 * LDR];
  const int tid  = threadIdx.x;
  const int bid  = blockIdx.y * 17 + blockIdx.x;      // 0..1087
  const int swz  = (bid & 7) * 136 + (bid >> 3);      // XCD-contiguous chunks
  const int row0 = (swz / 17) * 64, col0 = (swz % 17) * 64;
  const int srow = tid >> 2, sq = tid & 3;            // staging: row, quarter
  const int lane = tid & 63, w = tid >> 6;
  const int wr = (w >> 1) * 32, wc = (w & 1) * 32;
  const int fr = lane & 15, fg = lane >> 4;

  const unsigned short* gx = xh + (size_t)(row0 + srow) * KP;
  const unsigned short* gk = kh + (size_t)(col0 + srow) * KP;
  unsigned short* sa = As + srow * LDR + sq * 8;      // chunks at sq*8 and 32+sq*8
  unsigned short* sb = Bs + srow * LDR + sq * 8;
  const unsigned short* pa0 = As + (wr + fr) * LDR + fg * 8;
  const unsigned short* pb0 = Bs + (wc + fr) * LDR + fg * 8;

  uint4 va0 = *(const uint4*)(gx + sq * 8);
  uint4 va1 = *(const uint4*)(gx + 32 + sq * 8);
  uint4 vb0 = *(const uint4*)(gk + sq * 8);
  uint4 vb1 = *(const uint4*)(gk + 32 + sq * 8);

  f32x4 acc[2][2] = {};
  for (int t = 0; t < 13; ++t) {
    __syncthreads();
    *(uint4*)sa = va0; *(uint4*)(sa + 32) = va1;
    *(uint4*)sb = vb0; *(uint4*)(sb + 32) = vb1;
    __syncthreads();
    if (t < 12) {
      int k1 = (t + 1) * 64;
      va0 = *(const uint4*)(gx + k1 + sq * 8);
      va1 = *(const uint4*)(gx + k1 + 32 + sq * 8);
      vb0 = *(const uint4*)(gk + k1 + sq * 8);
      vb1 = *(const uint4*)(gk + k1 + 32 + sq * 8);
    }
    #pragma unroll
    for (int kk = 0; kk < 64; kk += 32) {
      s16x8 a0 = *(const s16x8*)(pa0 + kk);
      s16x8 a1 = *(const s16x8*)(pa0 + 16 * LDR + kk);
      s16x8 b0 = *(const s16x8*)(pb0 + kk);
      s16x8 b1 = *(const s16x8*)(pb0 + 16 * LDR + kk);
      acc[0][0] = __builtin_amdgcn_mfma_f32_16x16x32_bf16(a0, b0, acc[0][0], 0, 0, 0);
      acc[0][1] = __builtin_amdgcn_mfma_f32_16x16x32_bf16(a0, b1, acc[0][1], 0, 0, 0);
      acc[1][0] = __builtin_amdgcn_mfma_f32_16x16x32_bf16(a1, b0, acc[1][0], 0, 0, 0);
      acc[1][1] = __builtin_amdgcn_mfma_f32_16x16x32_bf16(a1, b1, acc[1][1], 0, 0, 0);
    }
  }
  #pragma unroll
  for (int m = 0; m < 2; ++m)
    #pragma unroll
    for (int n = 0; n < 2; ++n)
      #pragma unroll
      for (int j = 0; j < 4; ++j) {
        int r = row0 + wr + m * 16 + fg * 4 + j;
        int c = col0 + wc + n * 16 + fr;
        cosb[(size_t)r * NW + c] = acc[m][n][j];
      }
}

// ---- topk: one WAVE per row. Approx dots are the weights (scale-invariant ensemble);
//      exact fp32 refine only for boundary-ambiguous candidates. Heads fused. ----
__global__ __launch_bounds__(256) void topk_select(const float* __restrict__ cosb,
                                                   const float* __restrict__ x,
                                                   const float* __restrict__ keys,
                                                   const float* __restrict__ bv,
                                                   const float* __restrict__ bt,
                                                   float* __restrict__ sims,
                                                   int* __restrict__ count,
                                                   int* __restrict__ list,
                                                   float* __restrict__ out_tanh,
                                                   float* __restrict__ out_van) {
  __shared__ unsigned long long sKey[4][CAP];
  const int tid = threadIdx.x, w = tid >> 6, lane = tid & 63;
  const int row = (blockIdx.x << 2) + w;
  const float* cr = cosb + (size_t)row * NW;

  // ---- heads epilogue from cosb cols 1024..1043 ----
  {
    float hv = (lane < 20) ? cr[E_ + lane] : 0.f;
    float vv = 0.f, tv = 0.f;
    if (lane < 10) vv = hv + bv[lane];
    else if (lane < 20) tv = hv + bt[lane - 10];
    float mv = (lane < 10) ? vv : -__builtin_inff();
    #pragma unroll
    for (int off = 1; off < 16; off <<= 1) mv = fmaxf(mv, __shfl_xor(mv, off, 64));
    float ev = (lane < 10) ? expf(vv - mv) : 0.f;
    float se = ev;
    #pragma unroll
    for (int off = 1; off < 16; off <<= 1) se += __shfl_xor(se, off, 64);
    if (lane < 10) out_van[(size_t)row * C_ + lane] = vv - (mv + logf(se));
    else if (lane < 20) out_tanh[(size_t)row * C_ + (lane - 10)] = tanhf(tv * 0.1f) * 10.0f;
  }

  // ---- load the 1024 routing dots (cols 0..1023 only) ----
  float vals[16];
  #pragma unroll
  for (int j = 0; j < 16; ++j) vals[j] = cr[j * 64 + lane];
  float lm = vals[0];
  #pragma unroll
  for (int j = 1; j < 16; ++j) lm = fmaxf(lm, vals[j]);

  // threshold: 8th largest lane-max <= 8th largest value
  float srt = bitonic64_f(lm, lane);
  const float thr = __shfl(srt, 56) - MARG;

  // compact candidates (deterministic ballot-prefix order)
  int cnt = 0;
  #pragma unroll
  for (int j = 0; j < 16; ++j) {
    bool p = vals[j] >= thr;
    unsigned long long mk = __ballot(p);
    if (p) {
      int pos = cnt + __popcll(mk & ((1ull << lane) - 1ull));
      if (pos < CAP) sKey[w][pos] = packkey(vals[j], j * 64 + lane);
    }
    cnt += __popcll(mk);
  }
  const int m = cnt < CAP ? cnt : CAP;

  unsigned long long key = (lane < m) ? sKey[w][lane] : 0ull;
  key = bitonic64_u(key, lane);       // ascending; lanes 56..63 = approx top-8

  const float a8 = unpackval(__shfl(key, 56));
  const float a9 = unpackval(__shfl(key, 55));   // NaN if m == 8 (key 0)

  if (a8 - a9 <= MARG) {              // wave-uniform; false when a9 is NaN
    // boundary ambiguous: exact fp32 refine of window candidates
    const float4* xp4 = (const float4*)(x + (size_t)row * D_);
    float4 xr[4];
    #pragma unroll
    for (int i = 0; i < 3; ++i) xr[i] = xp4[i * 64 + lane];
    xr[3] = make_float4(0.f, 0.f, 0.f, 0.f);
    if (lane < 4) xr[3] = xp4[192 + lane];

    float myv = unpackval(key);
    unsigned long long rm = __ballot(key != 0ull && fabsf(myv - a8) <= MARG);
    while (rm) {
      int L = __builtin_ctzll(rm);
      rm &= rm - 1;
      unsigned long long kL = __shfl(key, L);
      int ei = (int)(~(unsigned)kL) & (E_ - 1);
      const float4* kp4 = (const float4*)(keys + (size_t)ei * D_);
      float s = 0.f;
      #pragma unroll
      for (int i = 0; i < 3; ++i) {
        float4 kv = kp4[i * 64 + lane];
        s += xr[i].x * kv.x + xr[i].y * kv.y + xr[i].z * kv.z + xr[i].w * kv.w;
      }
      if (lane < 4) {
        float4 kv = kp4[192 + lane];
        s += xr[3].x * kv.x + xr[3].y * kv.y + xr[3].z * kv.z + xr[3].w * kv.w;
      }
      s = wave_reduce_sum(s);
      if (lane == L) key = packkey(s, ei);
    }
    key = bitonic64_u(key, lane);     // re-rank with exact boundary values
  }

  // emit top-8: normalized weights by value-rank, bucket scatter by ascending id
  if (lane >= 56) {
    float simv = unpackval(key);
    int ei = (int)(~(unsigned)key) & (E_ - 1);
    float ssum = simv;
    ssum += __shfl_xor(ssum, 1, 64);
    ssum += __shfl_xor(ssum, 2, 64);
    ssum += __shfl_xor(ssum, 4, 64);
    sims[row * K_ + (63 - lane)] = simv / ssum;   // rank 0 = best
    int si = ei;
    const int l3 = lane & 7;
    #pragma unroll
    for (int k = 2; k <= 8; k <<= 1) {
      #pragma unroll
      for (int j = k >> 1; j > 0; j >>= 1) {
        int o = __shfl_xor(si, j, 64);
        bool lower = (l3 & j) == 0;
        bool asc = (l3 & k) == 0;
        int mn = si < o ? si : o;
        int mx = si < o ? o : si;
        si = (lower == asc) ? mn : mx;
      }
    }
    int pos = atomicAdd(&count[si], 1);
    if (pos < ECAP) list[si * ECAP + pos] = row * K_ + (lane - 56);
  }
}

// ---- per-expert bf16 MFMA, 2-way K-split x 2 sample-groups (all 4 waves active):
//      wave w: samples [ (w>>1)*16, +16 ), K-half (w&1). Partials combined in LDS,
//      then tanh -> weighted atomic scatter into out. ----
__global__ __launch_bounds__(256) void expert_mfma(const float* __restrict__ Wm,
                                                   const float* __restrict__ bm,
                                                   const unsigned short* __restrict__ xh,
                                                   const int* __restrict__ list,
                                                   const int* __restrict__ count,
                                                   const float* __restrict__ sims,
                                                   float* __restrict__ out_ens) {
  __shared__ unsigned short Wl[16 * LDW];
  __shared__ float cmb[2][16][17];   // [group][sample-in-16][class], padded
  const int e   = blockIdx.x;
  const int tid = threadIdx.x;
  int n = count[e];
  n = n < ECAP ? n : ECAP;
  const int base = e * ECAP;

  for (int ch = tid; ch < 16 * CHR; ch += 256) {
    int r  = ch / CHR;
    int kc = (ch % CHR) * 8;
    unsigned short u[8];
    if (r < 10 && kc < 784) {
      const float4* s4 = (const float4*)(Wm + (size_t)e * (C_ * D_) + r * D_ + kc);
      float4 f0 = s4[0], f1 = s4[1];
      __hip_bfloat16 h;
      h = __float2bfloat16(f0.x); u[0] = *(unsigned short*)&h;
      h = __float2bfloat16(f0.y); u[1] = *(unsigned short*)&h;
      h = __float2bfloat16(f0.z); u[2] = *(unsigned short*)&h;
      h = __float2bfloat16(f0.w); u[3] = *(unsigned short*)&h;
      h = __float2bfloat16(f1.x); u[4] = *(unsigned short*)&h;
      h = __float2bfloat16(f1.y); u[5] = *(unsigned short*)&h;
      h = __float2bfloat16(f1.z); u[6] = *(unsigned short*)&h;
      h = __float2bfloat16(f1.w); u[7] = *(unsigned short*)&h;
    } else {
      #pragma unroll
      for (int i = 0; i < 8; ++i) u[i] = 0;
    }
    *(uint4*)(Wl + r * LDW + kc) = *(uint4*)u;
  }
  __syncthreads();
  if (n == 0) return;

  const int lane = tid & 63, w = tid >> 6;
  const int g  = w >> 1;               // sample group
  const int kh = w & 1;                // K half
  const int fr = lane & 15, fg = lane >> 4;
  const float bias = (fr < C_) ? bm[e * C_ + fr] : 0.f;
  const unsigned short* bp = Wl + fr * LDW + kh * KH + fg * 8;

  for (int c0b = 0; c0b < n; c0b += 32) {
    const int c0 = c0b + g * 16;
    int sidx = c0 + fr;
    int item = (sidx < n) ? list[base + sidx] : list[base];
    const unsigned short* xrow = xh + (size_t)(item >> 3) * KP + kh * KH + fg * 8;
    f32x4 acc = {};
    #pragma unroll
    for (int k0 = 0; k0 < KH; k0 += 32) {
      s16x8 a = *(const s16x8*)(xrow + k0);
      s16x8 b = *(const s16x8*)(bp + k0);
      acc = __builtin_amdgcn_mfma_f32_16x16x32_bf16(a, b, acc, 0, 0, 0);
    }
    if (kh == 1) {
      #pragma unroll
      for (int j = 0; j < 4; ++j) cmb[g][fg * 4 + j][fr] = acc[j];
    }
    __syncthreads();
    if (kh == 0 && fr < C_) {
      #pragma unroll
      for (int j = 0; j < 4; ++j) {
        int s2 = c0 + fg * 4 + j;
        if (s2 < n) {
          int it2 = list[base + s2];
          float sum = acc[j] + cmb[g][fg * 4 + j][fr];
          float val = tanhf((sum + bias) * 0.1f) * 10.0f;
          atomicAdd(&out_ens[(size_t)(it2 >> 3) * C_ + fr], val * sims[it2]);
        }
      }
    }
    __syncthreads();   // cmb reuse guard for next iteration
  }
}

extern "C" void kernel_launch(void* const* d_in, const int* in_sizes, int n_in,
                              void* d_out, int out_size, void* d_ws, size_t ws_size,
                              hipStream_t stream) {
  const float* x    = (const float*)d_in[0];
  const float* keys = (const float*)d_in[1];
  const float* Wm   = (const float*)d_in[2];
  const float* bm   = (const float*)d_in[3];
  const float* Wv   = (const float*)d_in[4];
  const float* bv   = (const float*)d_in[5];
  const float* Wt   = (const float*)d_in[6];
  const float* bt   = (const float*)d_in[7];
  float* out = (float*)d_out;
  float* out_ens  = out;
  float* out_tanh = out + (size_t)B_ * C_;
  float* out_van  = out + 2 * (size_t)B_ * C_;

  char* p = (char*)d_ws;
  auto carve = [&](size_t bytes) { char* q = p; p += (bytes + 255) & ~(size_t)255; return q; };
  float* cosb  = (float*)carve((size_t)B_ * NW * 4);
  float* sims  = (float*)carve(B_ * K_ * 4);
  unsigned short* xh = (unsigned short*)carve((size_t)B_ * KP * 2);
  unsigned short* kh = (unsigned short*)carve((size_t)NW * KP * 2);
  int*   count  = (int*)carve(E_ * 4);
  int*   list   = (int*)carve((size_t)E_ * ECAP * 4);

  int prep_threads = B_ * CHR + NW * CHR + (B_ * C_) / 4;
  prep_all<<<(prep_threads + 255) / 256, 256, 0, stream>>>(x, keys, Wv, Wt, xh, kh,
                                                           out_ens, count);
  dim3 g(NW / 64, B_ / 64);   // (17, 64), swizzled inside
  gemm_bf16<<<g, 256, 0, stream>>>(xh, kh, cosb);
  topk_select<<<B_ / 4, 256, 0, stream>>>(cosb, x, keys, bv, bt, sims, count, list,
                                          out_tanh, out_van);
  expert_mfma<<<E_, 256, 0, stream>>>(Wm, bm, xh, list, count, sims, out_ens);
}